// Round 12
// baseline (235.133 us; speedup 1.0000x reference)
//
#include <hip/hip_runtime.h>
#include <hip/hip_bf16.h>
#include <math.h>
#include <stdint.h>

#define B_  256
#define N_  1024
#define D_  512
#define H_  2048
#define O_  512
#define M4  (4 * B_)
#define M12 (12 * B_)
#define NCH 8

typedef __attribute__((ext_vector_type(8))) short short8;
typedef __attribute__((ext_vector_type(4))) float f32x4;
typedef unsigned short ushort_t;

__device__ inline uint32_t pkbf(float a, float b) {
    union { __hip_bfloat162 h; uint32_t u; } cv;
    cv.h = __float22bfloat162_rn(float2{a, b});
    return cv.u;
}
__device__ inline ushort_t f2bf(float f) {
    union { float f; uint32_t u; } v; v.f = f;
    uint32_t r = v.u + 0x7FFFu + ((v.u >> 16) & 1u);
    return (ushort_t)(r >> 16);
}

__device__ inline void load_lds16(const void* g, void* l) {
    typedef const __attribute__((address_space(1))) uint32_t* gp_t;
    typedef __attribute__((address_space(3))) uint32_t* lp_t;
    __builtin_amdgcn_global_load_lds((gp_t)(uintptr_t)g, (lp_t)(uint32_t)(uintptr_t)l,
                                     16, 0, 0);
}

// grid barrier: all `target` blocks arrive; agent fences for cross-XCD visibility.
__device__ inline void gridbar(int* ctr, int target) {
    __syncthreads();
    if (threadIdx.x == 0) {
        __threadfence();                       // release: flush my writes
        atomicAdd(ctr, 1);
        while (atomicAdd(ctr, 0) < target) __builtin_amdgcn_s_sleep(2);
        __threadfence();                       // acquire: invalidate stale caches
    }
    __syncthreads();
}

// ---------------------------------------------------------------------------
// agg core: per (b, n-chunk) partials. NT loads, unroll 8.
// ---------------------------------------------------------------------------
__device__ __forceinline__ void agg_core(const float* __restrict__ x,
                                         const float* __restrict__ mask,
                                         float* __restrict__ part,
                                         float* __restrict__ cntp,
                                         int id, int t) {
    const int b    = id >> 2;
    const int c    = id & 3;
    const int half = t >> 7;
    const int d4   = (t & 127) << 2;
    const float* base = x + ((size_t)b * N_ + (size_t)c * 256) * D_ + d4;
    const float* mp   = mask + (size_t)b * N_ + (size_t)c * 256;

    f32x4 sum = {0.f,0.f,0.f,0.f}, sq = {0.f,0.f,0.f,0.f};
    f32x4 mx = {-INFINITY,-INFINITY,-INFINITY,-INFINITY};
    f32x4 mn = { INFINITY, INFINITY, INFINITY, INFINITY};
    float cnt = 0.f;

    #pragma unroll 8
    for (int n = half; n < 256; n += 2) {
        float m = mp[n];
        f32x4 v = __builtin_nontemporal_load((const f32x4*)(base + (size_t)n * D_));
        sum.x = fmaf(v.x, m, sum.x); sum.y = fmaf(v.y, m, sum.y);
        sum.z = fmaf(v.z, m, sum.z); sum.w = fmaf(v.w, m, sum.w);
        sq.x  = fmaf(v.x * v.x, m, sq.x); sq.y = fmaf(v.y * v.y, m, sq.y);
        sq.z  = fmaf(v.z * v.z, m, sq.z); sq.w = fmaf(v.w * v.w, m, sq.w);
        cnt  += m;
        bool um = m > 0.f;
        mx.x = um ? fmaxf(mx.x, v.x) : mx.x; mx.y = um ? fmaxf(mx.y, v.y) : mx.y;
        mx.z = um ? fmaxf(mx.z, v.z) : mx.z; mx.w = um ? fmaxf(mx.w, v.w) : mx.w;
        mn.x = um ? fminf(mn.x, v.x) : mn.x; mn.y = um ? fminf(mn.y, v.y) : mn.y;
        mn.z = um ? fminf(mn.z, v.z) : mn.z; mn.w = um ? fminf(mn.w, v.w) : mn.w;
    }

    const int ch = c * 2 + half;
    const size_t SS = (size_t)B_ * NCH * D_;
    const size_t pi = ((size_t)(b * NCH + ch)) * D_ + d4;
    *(f32x4*)(part + 0 * SS + pi) = sum;
    *(f32x4*)(part + 1 * SS + pi) = sq;
    *(f32x4*)(part + 2 * SS + pi) = mx;
    *(f32x4*)(part + 3 * SS + pi) = mn;
    if ((t & 127) == 0) cntp[b * NCH + ch] = cnt;
}

// ---------------------------------------------------------------------------
// K1 mega-kernel (unchanged)
// ---------------------------------------------------------------------------
__device__ void conv_tile(const float* __restrict__ in, ushort_t* __restrict__ out,
                          int R, int C, int bx, int by, float* tile) {
    const int t  = threadIdx.x;
    const int r0 = by << 5;
    const int c0 = bx << 5;
    const int tr = t >> 3;
    const int tc = (t & 7) << 2;

    float4 v = *(const float4*)(in + (size_t)(r0 + tr) * C + c0 + tc);
    tile[tr * 33 + tc + 0] = v.x; tile[tr * 33 + tc + 1] = v.y;
    tile[tr * 33 + tc + 2] = v.z; tile[tr * 33 + tc + 3] = v.w;
    __syncthreads();

    union { uint32_t u[2]; ushort4 us; } o;
    o.u[0] = pkbf(tile[(tc + 0) * 33 + tr], tile[(tc + 1) * 33 + tr]);
    o.u[1] = pkbf(tile[(tc + 2) * 33 + tr], tile[(tc + 3) * 33 + tr]);
    *(ushort4*)(out + (size_t)(c0 + tr) * R + r0 + tc) = o.us;
}

__global__ __launch_bounds__(256) void k1_mega(const float* __restrict__ x,
                                               const float* __restrict__ mask,
                                               const float* __restrict__ W1,
                                               const float* __restrict__ W2,
                                               const float* __restrict__ unpadded,
                                               float* __restrict__ part,
                                               float* __restrict__ cntp,
                                               ushort_t* __restrict__ W1t,
                                               ushort_t* __restrict__ W2t,
                                               float* __restrict__ scale) {
    __shared__ float smem[32 * 33];
    const int id = blockIdx.x;
    const int t  = threadIdx.x;

    if (id < 1024) {
        agg_core(x, mask, part, cntp, id, t);
    } else if (id < 2048) {
        const int tid = id - 1024;
        conv_tile(W1, W1t, D_, H_, tid & 63, tid >> 6, smem);
    } else if (id < 3072) {
        const int tid = id - 2048;
        conv_tile(W2, W2t, H_, O_, tid & 15, tid >> 4, smem);
    } else {
        float4 u4 = *(const float4*)(unpadded + t * 4);
        smem[t] = u4.x + u4.y + u4.z + u4.w;
        __syncthreads();
        for (int s = 128; s > 0; s >>= 1) {
            if (t < s) smem[t] += smem[t + s];
            __syncthreads();
        }
        const float delta = smem[0] + 1.0f;
        float uu[4] = {u4.x, u4.y, u4.z, u4.w};
        #pragma unroll
        for (int j = 0; j < 4; ++j) {
            const int i = t * 4 + j;
            const float logu = logf(uu[j] + 1.0f);
            scale[i]          = 1.0f;
            scale[M4 + i]     = logu / delta;
            scale[2 * M4 + i] = delta / logu;
        }
    }
}

// ---------------------------------------------------------------------------
// Tail mega-kernel: 512 blocks x 256 threads, all co-resident (64 KB LDS ->
// exactly 2 blocks/CU). Phases separated by software grid barriers.
//   P0 (blocks 0-255):  agg_final -> aggr
//   P1 (all 512):       gemm1_h: Z tile + epilogue writes 3 scaled h copies
//   P2 (blocks 0-383):  gemm2: out = h @ W2t^T + b2 (2 K-groups x 2 waves)
// ---------------------------------------------------------------------------
__global__ __launch_bounds__(256) void tail_coop(const float* __restrict__ part,
                                                 const float* __restrict__ cntp,
                                                 const float* __restrict__ scale,
                                                 const float* __restrict__ b1,
                                                 const ushort_t* __restrict__ W1t,
                                                 const ushort_t* __restrict__ W2t,
                                                 const float* __restrict__ b2,
                                                 ushort_t* __restrict__ aggr,
                                                 ushort_t* __restrict__ h,
                                                 float* __restrict__ out,
                                                 int* __restrict__ bar) {
    __shared__ char smem_raw[65536];
    const int id   = blockIdx.x;
    const int t    = threadIdx.x;
    const int wave = t >> 6;
    const int lane = t & 63;
    const int rl   = lane & 15;
    const int hi   = lane >> 4;
    const int lr   = lane >> 3;
    const int ksw  = ((lane & 7) ^ lr) << 3;

    // ---------------- P0: agg_final ----------------
    if (id < 256) {
        const int b = id;
        const int d = 2 * t;
        float cnt = 0.f;
        #pragma unroll
        for (int c = 0; c < NCH; ++c) cnt += cntp[b * NCH + c];

        const size_t SS = (size_t)B_ * NCH * D_;
        float2 sum = {0.f, 0.f}, sq = {0.f, 0.f};
        float2 mx = {-INFINITY, -INFINITY}, mn = {INFINITY, INFINITY};
        #pragma unroll
        for (int c = 0; c < NCH; ++c) {
            const size_t pi = ((size_t)(b * NCH + c)) * D_ + d;
            float2 s  = *(const float2*)(part + 0 * SS + pi);
            float2 q  = *(const float2*)(part + 1 * SS + pi);
            float2 vx = *(const float2*)(part + 2 * SS + pi);
            float2 vn = *(const float2*)(part + 3 * SS + pi);
            sum.x += s.x; sum.y += s.y;
            sq.x  += q.x; sq.y  += q.y;
            mx.x = fmaxf(mx.x, vx.x); mx.y = fmaxf(mx.y, vx.y);
            mn.x = fminf(mn.x, vn.x); mn.y = fminf(mn.y, vn.y);
        }
        const float ic = 1.f / cnt;
        float2 mean = {sum.x * ic, sum.y * ic};
        float2 var  = {fmaxf(sq.x * ic - mean.x * mean.x, 0.f),
                       fmaxf(sq.y * ic - mean.y * mean.y, 0.f)};

        *(uint32_t*)(aggr + (size_t)(0 * B_ + b) * D_ + d) = pkbf(mean.x, mean.y);
        *(uint32_t*)(aggr + (size_t)(1 * B_ + b) * D_ + d) = pkbf(mx.x, mx.y);
        *(uint32_t*)(aggr + (size_t)(2 * B_ + b) * D_ + d) = pkbf(mn.x, mn.y);
        *(uint32_t*)(aggr + (size_t)(3 * B_ + b) * D_ + d) = pkbf(sqrtf(var.x), sqrtf(var.y));
    }
    gridbar(&bar[0], 512);

    // ---------------- P1: gemm1_h ----------------
    {
        ushort_t* As0 = (ushort_t*)(smem_raw);
        ushort_t* As1 = (ushort_t*)(smem_raw + 8192);
        ushort_t* Bs0 = (ushort_t*)(smem_raw + 16384);
        ushort_t* Bs1 = (ushort_t*)(smem_raw + 24576);

        const int bx = id & 31;          // col-block (H/64 = 32)
        const int by = id >> 5;          // row-block (M4/64 = 16)
        const int wm = wave >> 1, wn = wave & 1;
        const int row0 = by << 6;
        const int col0 = bx << 6;

        const ushort_t* Ag0 = aggr + (size_t)(row0 + wave * 8 + lr) * D_ + ksw;
        const ushort_t* Ag1 = aggr + (size_t)(row0 + 32 + wave * 8 + lr) * D_ + ksw;
        const ushort_t* Bg0 = W1t + (size_t)(col0 + wave * 8 + lr) * D_ + ksw;
        const ushort_t* Bg1 = W1t + (size_t)(col0 + 32 + wave * 8 + lr) * D_ + ksw;
        const int ld0 = (wave * 8) * 64;
        const int ld1 = (32 + wave * 8) * 64;

        f32x4 acc[2][2] = {};
        ushort_t* Ac = As0; ushort_t* An = As1;
        ushort_t* Bc = Bs0; ushort_t* Bn = Bs1;

        load_lds16(Ag0, Ac + ld0); load_lds16(Ag1, Ac + ld1);
        load_lds16(Bg0, Bc + ld0); load_lds16(Bg1, Bc + ld1);
        __syncthreads();

        for (int tt = 0; tt < D_ / 64; ++tt) {
            const int k1 = (tt + 1) * 64;
            if (tt + 1 < D_ / 64) {
                load_lds16(Ag0 + k1, An + ld0); load_lds16(Ag1 + k1, An + ld1);
                load_lds16(Bg0 + k1, Bn + ld0); load_lds16(Bg1 + k1, Bn + ld1);
            }
            short8 av[2][2], bv[2][2];
            #pragma unroll
            for (int i = 0; i < 2; ++i) {
                const int ra = wm * 32 + i * 16 + rl;
                const int rb = wn * 32 + i * 16 + rl;
                #pragma unroll
                for (int k2 = 0; k2 < 2; ++k2) {
                    av[i][k2] = *(const short8*)(Ac + ra * 64 + (((k2 * 4 + hi) ^ (ra & 7)) << 3));
                    bv[i][k2] = *(const short8*)(Bc + rb * 64 + (((k2 * 4 + hi) ^ (rb & 7)) << 3));
                }
            }
            #pragma unroll
            for (int i = 0; i < 2; ++i)
                #pragma unroll
                for (int j = 0; j < 2; ++j)
                    #pragma unroll
                    for (int k2 = 0; k2 < 2; ++k2)
                        acc[i][j] = __builtin_amdgcn_mfma_f32_16x16x32_bf16(av[i][k2], bv[j][k2], acc[i][j], 0, 0, 0);
            __syncthreads();
            ushort_t* tp;
            tp = Ac; Ac = An; An = tp;
            tp = Bc; Bc = Bn; Bn = tp;
        }

        #pragma unroll
        for (int i = 0; i < 2; ++i) {
            #pragma unroll
            for (int v = 0; v < 4; ++v) {
                const int row = row0 + wm * 32 + i * 16 + hi * 4 + v;
                const float s1 = scale[M4 + row];
                const float s2 = scale[2 * M4 + row];
                #pragma unroll
                for (int j = 0; j < 2; ++j) {
                    const int col = col0 + wn * 32 + j * 16 + rl;
                    const float bb = b1[col];
                    const float z  = acc[i][j][v];
                    h[(size_t)row * H_ + col]            = f2bf(fmaxf(z + bb, 0.f));
                    h[(size_t)(M4 + row) * H_ + col]     = f2bf(fmaxf(fmaf(s1, z, bb), 0.f));
                    h[(size_t)(2 * M4 + row) * H_ + col] = f2bf(fmaxf(fmaf(s2, z, bb), 0.f));
                }
            }
        }
    }
    gridbar(&bar[1], 512);

    // ---------------- P2: gemm2 ----------------
    if (id < 384) {
        const int kg = wave >> 1;        // K-group 0/1
        const int w2 = wave & 1;         // wave within group
        const int xcd = id & 7;
        const int idx = id >> 3;
        const int rb  = xcd * 6 + (idx % 6);
        const int cb  = idx / 6;
        const int row0 = rb << 6;
        const int col0 = cb << 6;
        const int kbase = kg * (H_ / 2);

        char* gbase = smem_raw + kg * 32768;
        ushort_t* Abuf0 = (ushort_t*)(gbase);
        ushort_t* Abuf1 = (ushort_t*)(gbase + 8192);
        ushort_t* Bbuf0 = (ushort_t*)(gbase + 16384);
        ushort_t* Bbuf1 = (ushort_t*)(gbase + 24576);

        // wave w2 stages A rows [w2*32,+32) and B rows [w2*32,+32): 4 glds each
        const ushort_t* Ag = h   + (size_t)(row0 + w2 * 32 + lr) * H_ + kbase + ksw;
        const ushort_t* Bg = W2t + (size_t)(col0 + w2 * 32 + lr) * H_ + kbase + ksw;
        const int lda = (w2 * 32) * 64;

        f32x4 acc[2][4] = {};
        ushort_t* Ac = Abuf0; ushort_t* An = Abuf1;
        ushort_t* Bc = Bbuf0; ushort_t* Bn = Bbuf1;

        #pragma unroll
        for (int q = 0; q < 4; ++q) {
            load_lds16(Ag + (size_t)(q * 8) * H_, Ac + lda + q * 8 * 64);
            load_lds16(Bg + (size_t)(q * 8) * H_, Bc + lda + q * 8 * 64);
        }
        __syncthreads();

        for (int tt = 0; tt < 16; ++tt) {
            const int k1 = (tt + 1) * 64;
            if (tt + 1 < 16) {
                #pragma unroll
                for (int q = 0; q < 4; ++q) {
                    load_lds16(Ag + (size_t)(q * 8) * H_ + k1, An + lda + q * 8 * 64);
                    load_lds16(Bg + (size_t)(q * 8) * H_ + k1, Bn + lda + q * 8 * 64);
                }
            }
            short8 av[2][2], bv[4][2];
            #pragma unroll
            for (int i = 0; i < 2; ++i) {
                const int ra = w2 * 32 + i * 16 + rl;
                #pragma unroll
                for (int k2 = 0; k2 < 2; ++k2)
                    av[i][k2] = *(const short8*)(Ac + ra * 64 + (((k2 * 4 + hi) ^ (ra & 7)) << 3));
            }
            #pragma unroll
            for (int j = 0; j < 4; ++j) {
                const int rb2 = j * 16 + rl;
                #pragma unroll
                for (int k2 = 0; k2 < 2; ++k2)
                    bv[j][k2] = *(const short8*)(Bc + rb2 * 64 + (((k2 * 4 + hi) ^ (rb2 & 7)) << 3));
            }
            #pragma unroll
            for (int i = 0; i < 2; ++i)
                #pragma unroll
                for (int j = 0; j < 4; ++j)
                    #pragma unroll
                    for (int k2 = 0; k2 < 2; ++k2)
                        acc[i][j] = __builtin_amdgcn_mfma_f32_16x16x32_bf16(av[i][k2], bv[j][k2], acc[i][j], 0, 0, 0);
            __syncthreads();
            ushort_t* tp;
            tp = Ac; Ac = An; An = tp;
            tp = Bc; Bc = Bn; Bn = tp;
        }

        // combine the two K-halves through LDS (16 KB at smem base).
        float* red = (float*)smem_raw;
        const int fidx = (w2 * 64 + lane) * 32;
        if (kg == 1) {
            #pragma unroll
            for (int i = 0; i < 2; ++i)
                #pragma unroll
                for (int j = 0; j < 4; ++j)
                    #pragma unroll
                    for (int v = 0; v < 4; ++v)
                        red[fidx + i * 16 + j * 4 + v] = acc[i][j][v];
        }
        __syncthreads();
        if (kg == 0) {
            #pragma unroll
            for (int i = 0; i < 2; ++i)
                #pragma unroll
                for (int j = 0; j < 4; ++j) {
                    const int col = col0 + j * 16 + rl;
                    const float bb = b2[col];
                    #pragma unroll
                    for (int v = 0; v < 4; ++v) {
                        const int row = row0 + w2 * 32 + i * 16 + hi * 4 + v;
                        out[(size_t)row * O_ + col] =
                            acc[i][j][v] + red[fidx + i * 16 + j * 4 + v] + bb;
                    }
                }
        }
    }
}

// ---------------------------------------------------------------------------
extern "C" void kernel_launch(void* const* d_in, const int* in_sizes, int n_in,
                              void* d_out, int out_size, void* d_ws, size_t ws_size,
                              hipStream_t stream) {
    const float* x        = (const float*)d_in[0];
    const float* mask     = (const float*)d_in[1];
    const float* unpadded = (const float*)d_in[2];
    const float* W1       = (const float*)d_in[3];
    const float* b1       = (const float*)d_in[4];
    const float* W2       = (const float*)d_in[5];
    const float* b2       = (const float*)d_in[6];
    float* out = (float*)d_out;

    float* ws = (float*)d_ws;
    float* part  = ws;                        // 4,194,304 f32
    float* cntp  = ws + 4194304;              // 2048
    float* scale = ws + 4196352;              // 3072
    int*   bar   = (int*)(ws + 4199424);      // 16 ints
    ushort_t* bfw  = (ushort_t*)(ws + 4200448);
    ushort_t* W1t  = bfw;                     // 2048*512
    ushort_t* W2t  = bfw + 1048576;           // 512*2048
    ushort_t* aggr = bfw + 2097152;           // 1024*512
    ushort_t* h    = bfw + 2621440;           // 3072*2048 bf16

    hipMemsetAsync(bar, 0, 64, stream);
    k1_mega<<<3073, 256, 0, stream>>>(x, mask, W1, W2, unpadded,
                                      part, cntp, W1t, W2t, scale);
    tail_coop<<<512, 256, 0, stream>>>(part, cntp, scale, b1, W1t, W2t, b2,
                                       aggr, h, out, bar);
}

// Round 13
// 230.295 us; speedup vs baseline: 1.0210x; 1.0210x over previous
//
#include <hip/hip_runtime.h>
#include <hip/hip_bf16.h>
#include <math.h>
#include <stdint.h>

#define B_  256
#define N_  1024
#define D_  512
#define H_  2048
#define O_  512
#define M4  (4 * B_)
#define M12 (12 * B_)
#define NCH 8

typedef __attribute__((ext_vector_type(8))) short short8;
typedef __attribute__((ext_vector_type(4))) float f32x4;
typedef unsigned short ushort_t;

__device__ inline uint32_t pkbf(float a, float b) {
    union { __hip_bfloat162 h; uint32_t u; } cv;
    cv.h = __float22bfloat162_rn(float2{a, b});
    return cv.u;
}
__device__ inline ushort_t f2bf(float f) {
    union { float f; uint32_t u; } v; v.f = f;
    uint32_t r = v.u + 0x7FFFu + ((v.u >> 16) & 1u);
    return (ushort_t)(r >> 16);
}

__device__ inline void load_lds16(const void* g, void* l) {
    typedef const __attribute__((address_space(1))) uint32_t* gp_t;
    typedef __attribute__((address_space(3))) uint32_t* lp_t;
    __builtin_amdgcn_global_load_lds((gp_t)(uintptr_t)g, (lp_t)(uint32_t)(uintptr_t)l,
                                     16, 0, 0);
}

// grid barrier: arrival via one atomicAdd; spin via coherent atomic LOAD
// (agent scope, no RMW -> no cacheline ping-pong across XCDs).
__device__ inline void gridbar(int* ctr, int target) {
    __syncthreads();
    if (threadIdx.x == 0) {
        __threadfence();                       // release: flush my writes
        atomicAdd(ctr, 1);
        while (__hip_atomic_load(ctr, __ATOMIC_RELAXED,
                                 __HIP_MEMORY_SCOPE_AGENT) < target)
            __builtin_amdgcn_s_sleep(8);
        __threadfence();                       // acquire: discard stale caches
    }
    __syncthreads();
}

// ---------------------------------------------------------------------------
// agg core: per (b, n-chunk) partials. NT loads, unroll 8.
// ---------------------------------------------------------------------------
__device__ __forceinline__ void agg_core(const float* __restrict__ x,
                                         const float* __restrict__ mask,
                                         float* __restrict__ part,
                                         float* __restrict__ cntp,
                                         int id, int t) {
    const int b    = id >> 2;
    const int c    = id & 3;
    const int half = t >> 7;
    const int d4   = (t & 127) << 2;
    const float* base = x + ((size_t)b * N_ + (size_t)c * 256) * D_ + d4;
    const float* mp   = mask + (size_t)b * N_ + (size_t)c * 256;

    f32x4 sum = {0.f,0.f,0.f,0.f}, sq = {0.f,0.f,0.f,0.f};
    f32x4 mx = {-INFINITY,-INFINITY,-INFINITY,-INFINITY};
    f32x4 mn = { INFINITY, INFINITY, INFINITY, INFINITY};
    float cnt = 0.f;

    #pragma unroll 8
    for (int n = half; n < 256; n += 2) {
        float m = mp[n];
        f32x4 v = __builtin_nontemporal_load((const f32x4*)(base + (size_t)n * D_));
        sum.x = fmaf(v.x, m, sum.x); sum.y = fmaf(v.y, m, sum.y);
        sum.z = fmaf(v.z, m, sum.z); sum.w = fmaf(v.w, m, sum.w);
        sq.x  = fmaf(v.x * v.x, m, sq.x); sq.y = fmaf(v.y * v.y, m, sq.y);
        sq.z  = fmaf(v.z * v.z, m, sq.z); sq.w = fmaf(v.w * v.w, m, sq.w);
        cnt  += m;
        bool um = m > 0.f;
        mx.x = um ? fmaxf(mx.x, v.x) : mx.x; mx.y = um ? fmaxf(mx.y, v.y) : mx.y;
        mx.z = um ? fmaxf(mx.z, v.z) : mx.z; mx.w = um ? fmaxf(mx.w, v.w) : mx.w;
        mn.x = um ? fminf(mn.x, v.x) : mn.x; mn.y = um ? fminf(mn.y, v.y) : mn.y;
        mn.z = um ? fminf(mn.z, v.z) : mn.z; mn.w = um ? fminf(mn.w, v.w) : mn.w;
    }

    const int ch = c * 2 + half;
    const size_t SS = (size_t)B_ * NCH * D_;
    const size_t pi = ((size_t)(b * NCH + ch)) * D_ + d4;
    *(f32x4*)(part + 0 * SS + pi) = sum;
    *(f32x4*)(part + 1 * SS + pi) = sq;
    *(f32x4*)(part + 2 * SS + pi) = mx;
    *(f32x4*)(part + 3 * SS + pi) = mn;
    if ((t & 127) == 0) cntp[b * NCH + ch] = cnt;
}

// ---------------------------------------------------------------------------
// K1 mega-kernel (unchanged)
// ---------------------------------------------------------------------------
__device__ void conv_tile(const float* __restrict__ in, ushort_t* __restrict__ out,
                          int R, int C, int bx, int by, float* tile) {
    const int t  = threadIdx.x;
    const int r0 = by << 5;
    const int c0 = bx << 5;
    const int tr = t >> 3;
    const int tc = (t & 7) << 2;

    float4 v = *(const float4*)(in + (size_t)(r0 + tr) * C + c0 + tc);
    tile[tr * 33 + tc + 0] = v.x; tile[tr * 33 + tc + 1] = v.y;
    tile[tr * 33 + tc + 2] = v.z; tile[tr * 33 + tc + 3] = v.w;
    __syncthreads();

    union { uint32_t u[2]; ushort4 us; } o;
    o.u[0] = pkbf(tile[(tc + 0) * 33 + tr], tile[(tc + 1) * 33 + tr]);
    o.u[1] = pkbf(tile[(tc + 2) * 33 + tr], tile[(tc + 3) * 33 + tr]);
    *(ushort4*)(out + (size_t)(c0 + tr) * R + r0 + tc) = o.us;
}

__global__ __launch_bounds__(256) void k1_mega(const float* __restrict__ x,
                                               const float* __restrict__ mask,
                                               const float* __restrict__ W1,
                                               const float* __restrict__ W2,
                                               const float* __restrict__ unpadded,
                                               float* __restrict__ part,
                                               float* __restrict__ cntp,
                                               ushort_t* __restrict__ W1t,
                                               ushort_t* __restrict__ W2t,
                                               float* __restrict__ scale) {
    __shared__ float smem[32 * 33];
    const int id = blockIdx.x;
    const int t  = threadIdx.x;

    if (id < 1024) {
        agg_core(x, mask, part, cntp, id, t);
    } else if (id < 2048) {
        const int tid = id - 1024;
        conv_tile(W1, W1t, D_, H_, tid & 63, tid >> 6, smem);
    } else if (id < 3072) {
        const int tid = id - 2048;
        conv_tile(W2, W2t, H_, O_, tid & 15, tid >> 4, smem);
    } else {
        float4 u4 = *(const float4*)(unpadded + t * 4);
        smem[t] = u4.x + u4.y + u4.z + u4.w;
        __syncthreads();
        for (int s = 128; s > 0; s >>= 1) {
            if (t < s) smem[t] += smem[t + s];
            __syncthreads();
        }
        const float delta = smem[0] + 1.0f;
        float uu[4] = {u4.x, u4.y, u4.z, u4.w};
        #pragma unroll
        for (int j = 0; j < 4; ++j) {
            const int i = t * 4 + j;
            const float logu = logf(uu[j] + 1.0f);
            scale[i]          = 1.0f;
            scale[M4 + i]     = logu / delta;
            scale[2 * M4 + i] = delta / logu;
        }
    }
}

// ---------------------------------------------------------------------------
// Tail mega-kernel: 512 blocks x 256 threads, all co-resident (64 KB LDS ->
// exactly 2 blocks/CU). Phases separated by software grid barriers.
//   P0 (blocks 0-255):  agg_final -> aggr
//   P1 (all 512):       gemm1_h: Z tile + epilogue writes 3 scaled h copies
//   P2 (blocks 0-383):  gemm2: out = h @ W2t^T + b2 (2 K-groups x 2 waves)
// ---------------------------------------------------------------------------
__global__ __launch_bounds__(256) void tail_coop(const float* __restrict__ part,
                                                 const float* __restrict__ cntp,
                                                 const float* __restrict__ scale,
                                                 const float* __restrict__ b1,
                                                 const ushort_t* __restrict__ W1t,
                                                 const ushort_t* __restrict__ W2t,
                                                 const float* __restrict__ b2,
                                                 ushort_t* __restrict__ aggr,
                                                 ushort_t* __restrict__ h,
                                                 float* __restrict__ out,
                                                 int* __restrict__ bar) {
    __shared__ char smem_raw[65536];
    const int id   = blockIdx.x;
    const int t    = threadIdx.x;
    const int wave = t >> 6;
    const int lane = t & 63;
    const int rl   = lane & 15;
    const int hi   = lane >> 4;
    const int lr   = lane >> 3;
    const int ksw  = ((lane & 7) ^ lr) << 3;

    // ---------------- P0: agg_final ----------------
    if (id < 256) {
        const int b = id;
        const int d = 2 * t;
        float cnt = 0.f;
        #pragma unroll
        for (int c = 0; c < NCH; ++c) cnt += cntp[b * NCH + c];

        const size_t SS = (size_t)B_ * NCH * D_;
        float2 sum = {0.f, 0.f}, sq = {0.f, 0.f};
        float2 mx = {-INFINITY, -INFINITY}, mn = {INFINITY, INFINITY};
        #pragma unroll
        for (int c = 0; c < NCH; ++c) {
            const size_t pi = ((size_t)(b * NCH + c)) * D_ + d;
            float2 s  = *(const float2*)(part + 0 * SS + pi);
            float2 q  = *(const float2*)(part + 1 * SS + pi);
            float2 vx = *(const float2*)(part + 2 * SS + pi);
            float2 vn = *(const float2*)(part + 3 * SS + pi);
            sum.x += s.x; sum.y += s.y;
            sq.x  += q.x; sq.y  += q.y;
            mx.x = fmaxf(mx.x, vx.x); mx.y = fmaxf(mx.y, vx.y);
            mn.x = fminf(mn.x, vn.x); mn.y = fminf(mn.y, vn.y);
        }
        const float ic = 1.f / cnt;
        float2 mean = {sum.x * ic, sum.y * ic};
        float2 var  = {fmaxf(sq.x * ic - mean.x * mean.x, 0.f),
                       fmaxf(sq.y * ic - mean.y * mean.y, 0.f)};

        *(uint32_t*)(aggr + (size_t)(0 * B_ + b) * D_ + d) = pkbf(mean.x, mean.y);
        *(uint32_t*)(aggr + (size_t)(1 * B_ + b) * D_ + d) = pkbf(mx.x, mx.y);
        *(uint32_t*)(aggr + (size_t)(2 * B_ + b) * D_ + d) = pkbf(mn.x, mn.y);
        *(uint32_t*)(aggr + (size_t)(3 * B_ + b) * D_ + d) = pkbf(sqrtf(var.x), sqrtf(var.y));
    }
    gridbar(&bar[0], 512);

    // ---------------- P1: gemm1_h ----------------
    {
        ushort_t* As0 = (ushort_t*)(smem_raw);
        ushort_t* As1 = (ushort_t*)(smem_raw + 8192);
        ushort_t* Bs0 = (ushort_t*)(smem_raw + 16384);
        ushort_t* Bs1 = (ushort_t*)(smem_raw + 24576);

        const int bx = id & 31;          // col-block (H/64 = 32)
        const int by = id >> 5;          // row-block (M4/64 = 16)
        const int wm = wave >> 1, wn = wave & 1;
        const int row0 = by << 6;
        const int col0 = bx << 6;

        const ushort_t* Ag0 = aggr + (size_t)(row0 + wave * 8 + lr) * D_ + ksw;
        const ushort_t* Ag1 = aggr + (size_t)(row0 + 32 + wave * 8 + lr) * D_ + ksw;
        const ushort_t* Bg0 = W1t + (size_t)(col0 + wave * 8 + lr) * D_ + ksw;
        const ushort_t* Bg1 = W1t + (size_t)(col0 + 32 + wave * 8 + lr) * D_ + ksw;
        const int ld0 = (wave * 8) * 64;
        const int ld1 = (32 + wave * 8) * 64;

        f32x4 acc[2][2] = {};
        ushort_t* Ac = As0; ushort_t* An = As1;
        ushort_t* Bc = Bs0; ushort_t* Bn = Bs1;

        load_lds16(Ag0, Ac + ld0); load_lds16(Ag1, Ac + ld1);
        load_lds16(Bg0, Bc + ld0); load_lds16(Bg1, Bc + ld1);
        __syncthreads();

        for (int tt = 0; tt < D_ / 64; ++tt) {
            const int k1 = (tt + 1) * 64;
            if (tt + 1 < D_ / 64) {
                load_lds16(Ag0 + k1, An + ld0); load_lds16(Ag1 + k1, An + ld1);
                load_lds16(Bg0 + k1, Bn + ld0); load_lds16(Bg1 + k1, Bn + ld1);
            }
            short8 av[2][2], bv[2][2];
            #pragma unroll
            for (int i = 0; i < 2; ++i) {
                const int ra = wm * 32 + i * 16 + rl;
                const int rb = wn * 32 + i * 16 + rl;
                #pragma unroll
                for (int k2 = 0; k2 < 2; ++k2) {
                    av[i][k2] = *(const short8*)(Ac + ra * 64 + (((k2 * 4 + hi) ^ (ra & 7)) << 3));
                    bv[i][k2] = *(const short8*)(Bc + rb * 64 + (((k2 * 4 + hi) ^ (rb & 7)) << 3));
                }
            }
            #pragma unroll
            for (int i = 0; i < 2; ++i)
                #pragma unroll
                for (int j = 0; j < 2; ++j)
                    #pragma unroll
                    for (int k2 = 0; k2 < 2; ++k2)
                        acc[i][j] = __builtin_amdgcn_mfma_f32_16x16x32_bf16(av[i][k2], bv[j][k2], acc[i][j], 0, 0, 0);
            __syncthreads();
            ushort_t* tp;
            tp = Ac; Ac = An; An = tp;
            tp = Bc; Bc = Bn; Bn = tp;
        }

        #pragma unroll
        for (int i = 0; i < 2; ++i) {
            #pragma unroll
            for (int v = 0; v < 4; ++v) {
                const int row = row0 + wm * 32 + i * 16 + hi * 4 + v;
                const float s1 = scale[M4 + row];
                const float s2 = scale[2 * M4 + row];
                #pragma unroll
                for (int j = 0; j < 2; ++j) {
                    const int col = col0 + wn * 32 + j * 16 + rl;
                    const float bb = b1[col];
                    const float z  = acc[i][j][v];
                    h[(size_t)row * H_ + col]            = f2bf(fmaxf(z + bb, 0.f));
                    h[(size_t)(M4 + row) * H_ + col]     = f2bf(fmaxf(fmaf(s1, z, bb), 0.f));
                    h[(size_t)(2 * M4 + row) * H_ + col] = f2bf(fmaxf(fmaf(s2, z, bb), 0.f));
                }
            }
        }
    }
    gridbar(&bar[1], 512);

    // ---------------- P2: gemm2 ----------------
    if (id < 384) {
        const int kg = wave >> 1;        // K-group 0/1
        const int w2 = wave & 1;         // wave within group
        const int xcd = id & 7;
        const int idx = id >> 3;
        const int rb  = xcd * 6 + (idx % 6);
        const int cb  = idx / 6;
        const int row0 = rb << 6;
        const int col0 = cb << 6;
        const int kbase = kg * (H_ / 2);

        char* gbase = smem_raw + kg * 32768;
        ushort_t* Abuf0 = (ushort_t*)(gbase);
        ushort_t* Abuf1 = (ushort_t*)(gbase + 8192);
        ushort_t* Bbuf0 = (ushort_t*)(gbase + 16384);
        ushort_t* Bbuf1 = (ushort_t*)(gbase + 24576);

        const ushort_t* Ag = h   + (size_t)(row0 + w2 * 32 + lr) * H_ + kbase + ksw;
        const ushort_t* Bg = W2t + (size_t)(col0 + w2 * 32 + lr) * H_ + kbase + ksw;
        const int lda = (w2 * 32) * 64;

        f32x4 acc[2][4] = {};
        ushort_t* Ac = Abuf0; ushort_t* An = Abuf1;
        ushort_t* Bc = Bbuf0; ushort_t* Bn = Bbuf1;

        #pragma unroll
        for (int q = 0; q < 4; ++q) {
            load_lds16(Ag + (size_t)(q * 8) * H_, Ac + lda + q * 8 * 64);
            load_lds16(Bg + (size_t)(q * 8) * H_, Bc + lda + q * 8 * 64);
        }
        __syncthreads();

        for (int tt = 0; tt < 16; ++tt) {
            const int k1 = (tt + 1) * 64;
            if (tt + 1 < 16) {
                #pragma unroll
                for (int q = 0; q < 4; ++q) {
                    load_lds16(Ag + (size_t)(q * 8) * H_ + k1, An + lda + q * 8 * 64);
                    load_lds16(Bg + (size_t)(q * 8) * H_ + k1, Bn + lda + q * 8 * 64);
                }
            }
            short8 av[2][2], bv[4][2];
            #pragma unroll
            for (int i = 0; i < 2; ++i) {
                const int ra = w2 * 32 + i * 16 + rl;
                #pragma unroll
                for (int k2 = 0; k2 < 2; ++k2)
                    av[i][k2] = *(const short8*)(Ac + ra * 64 + (((k2 * 4 + hi) ^ (ra & 7)) << 3));
            }
            #pragma unroll
            for (int j = 0; j < 4; ++j) {
                const int rb2 = j * 16 + rl;
                #pragma unroll
                for (int k2 = 0; k2 < 2; ++k2)
                    bv[j][k2] = *(const short8*)(Bc + rb2 * 64 + (((k2 * 4 + hi) ^ (rb2 & 7)) << 3));
            }
            #pragma unroll
            for (int i = 0; i < 2; ++i)
                #pragma unroll
                for (int j = 0; j < 4; ++j)
                    #pragma unroll
                    for (int k2 = 0; k2 < 2; ++k2)
                        acc[i][j] = __builtin_amdgcn_mfma_f32_16x16x32_bf16(av[i][k2], bv[j][k2], acc[i][j], 0, 0, 0);
            __syncthreads();
            ushort_t* tp;
            tp = Ac; Ac = An; An = tp;
            tp = Bc; Bc = Bn; Bn = tp;
        }

        // combine the two K-halves through LDS (16 KB at smem base).
        float* red = (float*)smem_raw;
        const int fidx = (w2 * 64 + lane) * 32;
        if (kg == 1) {
            #pragma unroll
            for (int i = 0; i < 2; ++i)
                #pragma unroll
                for (int j = 0; j < 4; ++j)
                    #pragma unroll
                    for (int v = 0; v < 4; ++v)
                        red[fidx + i * 16 + j * 4 + v] = acc[i][j][v];
        }
        __syncthreads();
        if (kg == 0) {
            #pragma unroll
            for (int i = 0; i < 2; ++i)
                #pragma unroll
                for (int j = 0; j < 4; ++j) {
                    const int col = col0 + j * 16 + rl;
                    const float bb = b2[col];
                    #pragma unroll
                    for (int v = 0; v < 4; ++v) {
                        const int row = row0 + w2 * 32 + i * 16 + hi * 4 + v;
                        out[(size_t)row * O_ + col] =
                            acc[i][j][v] + red[fidx + i * 16 + j * 4 + v] + bb;
                    }
                }
        }
    }
}

// ---------------------------------------------------------------------------
extern "C" void kernel_launch(void* const* d_in, const int* in_sizes, int n_in,
                              void* d_out, int out_size, void* d_ws, size_t ws_size,
                              hipStream_t stream) {
    const float* x        = (const float*)d_in[0];
    const float* mask     = (const float*)d_in[1];
    const float* unpadded = (const float*)d_in[2];
    const float* W1       = (const float*)d_in[3];
    const float* b1       = (const float*)d_in[4];
    const float* W2       = (const float*)d_in[5];
    const float* b2       = (const float*)d_in[6];
    float* out = (float*)d_out;

    float* ws = (float*)d_ws;
    float* part  = ws;                        // 4,194,304 f32
    float* cntp  = ws + 4194304;              // 2048
    float* scale = ws + 4196352;              // 3072
    int*   bar   = (int*)(ws + 4199424);      // 16 ints
    ushort_t* bfw  = (ushort_t*)(ws + 4200448);
    ushort_t* W1t  = bfw;                     // 2048*512
    ushort_t* W2t  = bfw + 1048576;           // 512*2048
    ushort_t* aggr = bfw + 2097152;           // 1024*512
    ushort_t* h    = bfw + 2621440;           // 3072*2048 bf16

    hipMemsetAsync(bar, 0, 64, stream);
    k1_mega<<<3073, 256, 0, stream>>>(x, mask, W1, W2, unpadded,
                                      part, cntp, W1t, W2t, scale);
    tail_coop<<<512, 256, 0, stream>>>(part, cntp, scale, b1, W1t, W2t, b2,
                                       aggr, h, out, bar);
}